// Round 1
// baseline (740.468 us; speedup 1.0000x reference)
//
#include <hip/hip_runtime.h>
#include <hip/hip_bf16.h>
#include <stdint.h>

// Problem constants
#define NTOK   64      // tokens per window
#define CDIM   256     // embed dim
#define NHEAD  8
#define DHEAD  32
#define NWIN   256     // windows per image (mask count)
#define BWIN   2048    // total windows
#define MROWS  131072  // BWIN*NTOK

typedef __attribute__((ext_vector_type(8))) short short8;
typedef __attribute__((ext_vector_type(4))) float f32x4;

__device__ __forceinline__ ushort f2bf(float f) {
  uint32_t u = __float_as_uint(f);
  u += 0x7fffu + ((u >> 16) & 1u);   // RNE
  return (ushort)(u >> 16);
}
__device__ __forceinline__ void unpack8(uint4 u, float* f) {
  f[0] = __uint_as_float(u.x << 16);
  f[1] = __uint_as_float(u.x & 0xffff0000u);
  f[2] = __uint_as_float(u.y << 16);
  f[3] = __uint_as_float(u.y & 0xffff0000u);
  f[4] = __uint_as_float(u.z << 16);
  f[5] = __uint_as_float(u.z & 0xffff0000u);
  f[6] = __uint_as_float(u.w << 16);
  f[7] = __uint_as_float(u.w & 0xffff0000u);
}

// ---------------- tiny prep kernels ----------------

__global__ void k_cast_bf16(const float* __restrict__ src, ushort* __restrict__ dst, int n4) {
  int i = blockIdx.x * blockDim.x + threadIdx.x;
  int stride = gridDim.x * blockDim.x;
  for (; i < n4; i += stride) {
    float4 v = ((const float4*)src)[i];
    ushort4 o;
    o.x = f2bf(v.x); o.y = f2bf(v.y); o.z = f2bf(v.z); o.w = f2bf(v.w);
    ((ushort4*)dst)[i] = o;
  }
}

// src[K][N] fp32 -> dst[N][K] bf16
__global__ void k_transpose_bf16(const float* __restrict__ src, ushort* __restrict__ dst, int K, int N) {
  int idx = blockIdx.x * 256 + threadIdx.x;
  if (idx < N * K) {
    int n = idx / K, k = idx - n * K;
    dst[idx] = f2bf(src[(size_t)k * N + n]);
  }
}

// CPB MLP: bias_table[225][8]
__global__ void k_cpb(const float* __restrict__ ct, const float* __restrict__ w1,
                      const float* __restrict__ b1, const float* __restrict__ w2,
                      float* __restrict__ out) {
  int p = blockIdx.x, t = threadIdx.x;
  float c0 = ct[p * 2], c1 = ct[p * 2 + 1];
  float acc[8];
#pragma unroll
  for (int h = 0; h < 8; ++h) acc[h] = 0.f;
  for (int j = t; j < 512; j += 256) {
    float hj = fmaxf(0.f, fmaf(c0, w1[j], fmaf(c1, w1[512 + j], b1[j])));
#pragma unroll
    for (int h = 0; h < 8; ++h) acc[h] = fmaf(hj, w2[j * 8 + h], acc[h]);
  }
#pragma unroll
  for (int off = 1; off < 64; off <<= 1)
#pragma unroll
    for (int h = 0; h < 8; ++h) acc[h] += __shfl_xor(acc[h], off, 64);
  __shared__ float red[4][8];
  if ((t & 63) == 0)
#pragma unroll
    for (int h = 0; h < 8; ++h) red[t >> 6][h] = acc[h];
  __syncthreads();
  if (t < 8) out[p * 8 + t] = red[0][t] + red[1][t] + red[2][t] + red[3][t];
}

// relb[h][r][c] = 16*sigmoid(bias_table[rpi[r*64+c]][h])
__global__ void k_relb(const float* __restrict__ bt, const int* __restrict__ rpi,
                       float* __restrict__ relb) {
  int idx = blockIdx.x * 256 + threadIdx.x;  // 32768 total
  int h = idx >> 12, rc = idx & 4095;
  int p = rpi[rc];
  float v = bt[p * 8 + h];
  relb[idx] = 16.0f / (1.0f + __expf(-v));
}

// ---------------- MFMA GEMM: C[M][N] = A[M][K] * BT[N][K]^T ----------------
// A, BT bf16 row-major. 128x128 tile, BK=64, 256 threads (4 waves, each 64x64).
// LDS layout: 16B chunk (m, c) stored at chunk index m*8 + (c ^ (m&7))  (swizzle
// keeps both staging writes and frag reads bank-conflict-free).
// MODE 0: bf16 out, qkv bias (q_bias | 0 | v_bias).  MODE 1: fp32 out, bias0[j].
template <int MODE>
__global__ __launch_bounds__(256, 2) void gemm_bt(const ushort* __restrict__ A,
                                                  const ushort* __restrict__ BT,
                                                  void* __restrict__ Cout,
                                                  const float* __restrict__ bias0,
                                                  const float* __restrict__ bias1,
                                                  int K, int N) {
  __shared__ ushort As[128 * 64];
  __shared__ ushort Bs[128 * 64];
  const int t = threadIdx.x;
  const int bn = blockIdx.x, bm = blockIdx.y;
  const int wv = t >> 6, lane = t & 63, quad = lane >> 4, l16 = lane & 15;
  const int mbase = (wv & 1) * 64, nbase = (wv >> 1) * 64;

  f32x4 acc[4][4] = {};

  const int nkt = K >> 6;
  for (int kt = 0; kt < nkt; ++kt) {
    __syncthreads();
#pragma unroll
    for (int i = 0; i < 4; ++i) {
      int idx = i * 256 + t;
      int m = idx >> 3, c = idx & 7;
      int sw = (m * 8 + (c ^ (m & 7))) * 8;
      *(uint4*)(As + sw) = *(const uint4*)(A + (size_t)(bm * 128 + m) * K + kt * 64 + c * 8);
      *(uint4*)(Bs + sw) = *(const uint4*)(BT + (size_t)(bn * 128 + m) * K + kt * 64 + c * 8);
    }
    __syncthreads();
#pragma unroll
    for (int k2 = 0; k2 < 2; ++k2) {
      const int cidx = (k2 * 4 + quad) ^ (l16 & 7);
      short8 a[4], b[4];
#pragma unroll
      for (int mt = 0; mt < 4; ++mt)
        a[mt] = *(const short8*)(As + ((mbase + mt * 16 + l16) * 8 + cidx) * 8);
#pragma unroll
      for (int nt = 0; nt < 4; ++nt)
        b[nt] = *(const short8*)(Bs + ((nbase + nt * 16 + l16) * 8 + cidx) * 8);
#pragma unroll
      for (int mt = 0; mt < 4; ++mt)
#pragma unroll
        for (int nt = 0; nt < 4; ++nt)
          acc[mt][nt] = __builtin_amdgcn_mfma_f32_16x16x32_bf16(a[mt], b[nt], acc[mt][nt], 0, 0, 0);
    }
  }

#pragma unroll
  for (int mt = 0; mt < 4; ++mt)
#pragma unroll
    for (int nt = 0; nt < 4; ++nt) {
      int j = bn * 128 + nbase + nt * 16 + l16;
      int gm = bm * 128 + mbase + mt * 16 + quad * 4;
      float bs;
      if (MODE == 0) bs = (j < 256) ? bias0[j] : ((j < 512) ? 0.0f : bias1[j - 512]);
      else bs = bias0[j];
#pragma unroll
      for (int i2 = 0; i2 < 4; ++i2) {
        float v = acc[mt][nt][i2] + bs;
        size_t off = (size_t)(gm + i2) * N + j;
        if (MODE == 0) ((ushort*)Cout)[off] = f2bf(v);
        else ((float*)Cout)[off] = v;
      }
    }
}

// ---------------- fused cosine attention (fp32 vector math) ----------------
// One block per window; 4 waves; wave = head-sub; thread = (head, query row).
// K/V for 4 heads staged bf16 in LDS; all main-loop LDS reads are wave-uniform
// (broadcast, conflict-free).
__global__ __launch_bounds__(256, 2) void k_attn(const ushort* __restrict__ qkv,
                                                 const float* __restrict__ mask,
                                                 const float* __restrict__ ls,
                                                 const float* __restrict__ relb,
                                                 ushort* __restrict__ aob) {
  __shared__ uint4 kb[4][64][5];   // [head-sub][key][4 used chunks + pad]
  __shared__ uint4 vb[4][64][5];
  __shared__ float knorm[4][64];
  const int b = blockIdx.x, t = threadIdx.x;
  const int wi = b & (NWIN - 1);
  const int hs = t >> 6, r = t & 63;

  for (int pass = 0; pass < 2; ++pass) {
    __syncthreads();  // protect LDS reuse across passes
    // stage k, v for heads pass*4 .. pass*4+3
#pragma unroll
    for (int i = 0; i < 4; ++i) {
      int idx = i * 256 + t;          // 1024 16B-chunks per matrix
      int hh = idx >> 8;
      int row = (idx >> 2) & 63;
      int c4 = idx & 3;
      int h = pass * 4 + hh;
      size_t base = ((size_t)b * 64 + row) * 768 + h * 32 + c4 * 8;
      kb[hh][row][c4] = *(const uint4*)(qkv + base + 256);
      vb[hh][row][c4] = *(const uint4*)(qkv + base + 512);
    }
    __syncthreads();
    // per-key 1/||k||
    {
      float s = 0.f;
#pragma unroll
      for (int c4 = 0; c4 < 4; ++c4) {
        float f[8];
        unpack8(kb[hs][r][c4], f);
#pragma unroll
        for (int j = 0; j < 8; ++j) s = fmaf(f[j], f[j], s);
      }
      knorm[hs][r] = 1.0f / fmaxf(sqrtf(s), 1e-12f);
    }
    __syncthreads();

    const int h = pass * 4 + hs;
    // load + normalize q row, fold in logit scale
    float q[32];
    {
      size_t base = ((size_t)b * 64 + r) * 768 + h * 32;
      float s = 0.f;
#pragma unroll
      for (int c4 = 0; c4 < 4; ++c4) {
        unpack8(*(const uint4*)(qkv + base + c4 * 8), q + c4 * 8);
#pragma unroll
        for (int j = 0; j < 8; ++j) s = fmaf(q[c4 * 8 + j], q[c4 * 8 + j], s);
      }
      float sc = __expf(fminf(ls[h], 4.6051701859880914f)) / fmaxf(sqrtf(s), 1e-12f);
#pragma unroll
      for (int d = 0; d < 32; ++d) q[d] *= sc;
    }
    // logits
    float lg[64];
    const float4* rb4 = (const float4*)(relb + h * 4096 + r * 64);
    const float4* mk4 = (const float4*)(mask + (size_t)wi * 4096 + r * 64);
#pragma unroll 4
    for (int cg = 0; cg < 16; ++cg) {
      float4 rbv = rb4[cg];
      float4 mkv = mk4[cg];
      float rbf[4] = {rbv.x, rbv.y, rbv.z, rbv.w};
      float mkf[4] = {mkv.x, mkv.y, mkv.z, mkv.w};
#pragma unroll
      for (int ci = 0; ci < 4; ++ci) {
        int c = cg * 4 + ci;
        float dot = 0.f;
#pragma unroll
        for (int c4 = 0; c4 < 4; ++c4) {
          float f[8];
          unpack8(kb[hs][c][c4], f);
#pragma unroll
          for (int j = 0; j < 8; ++j) dot = fmaf(q[c4 * 8 + j], f[j], dot);
        }
        lg[c] = fmaf(dot, knorm[hs][c], rbf[ci] + mkf[ci]);
      }
    }
    // softmax (unnormalized p in lg, scale at the end)
    float m = lg[0];
#pragma unroll
    for (int c = 1; c < 64; ++c) m = fmaxf(m, lg[c]);
    float s = 0.f;
#pragma unroll
    for (int c = 0; c < 64; ++c) { lg[c] = __expf(lg[c] - m); s += lg[c]; }
    float inv = 1.0f / s;
    // PV
    float o[32];
#pragma unroll
    for (int d = 0; d < 32; ++d) o[d] = 0.f;
#pragma unroll 4
    for (int c = 0; c < 64; ++c) {
      float p = lg[c];
#pragma unroll
      for (int c4 = 0; c4 < 4; ++c4) {
        float f[8];
        unpack8(vb[hs][c][c4], f);
#pragma unroll
        for (int j = 0; j < 8; ++j) o[c4 * 8 + j] = fmaf(p, f[j], o[c4 * 8 + j]);
      }
    }
    // store bf16 row
    size_t ob = ((size_t)b * 64 + r) * 256 + h * 32;
#pragma unroll
    for (int g = 0; g < 4; ++g) {
      uint4 u;
      u.x = ((uint)f2bf(o[g * 8 + 1] * inv) << 16) | f2bf(o[g * 8 + 0] * inv);
      u.y = ((uint)f2bf(o[g * 8 + 3] * inv) << 16) | f2bf(o[g * 8 + 2] * inv);
      u.z = ((uint)f2bf(o[g * 8 + 5] * inv) << 16) | f2bf(o[g * 8 + 4] * inv);
      u.w = ((uint)f2bf(o[g * 8 + 7] * inv) << 16) | f2bf(o[g * 8 + 6] * inv);
      ((uint4*)(aob + ob))[g] = u;
    }
  }
}

// ---------------- launch ----------------

extern "C" void kernel_launch(void* const* d_in, const int* in_sizes, int n_in,
                              void* d_out, int out_size, void* d_ws, size_t ws_size,
                              hipStream_t stream) {
  const float* x      = (const float*)d_in[0];
  const float* mask   = (const float*)d_in[1];
  const float* qkv_w  = (const float*)d_in[2];
  const float* q_bias = (const float*)d_in[3];
  const float* v_bias = (const float*)d_in[4];
  const float* lscale = (const float*)d_in[5];
  const float* ctbl   = (const float*)d_in[6];
  const float* m1w    = (const float*)d_in[7];
  const float* m1b    = (const float*)d_in[8];
  const float* m2w    = (const float*)d_in[9];
  const float* projw  = (const float*)d_in[10];
  const float* projb  = (const float*)d_in[11];
  const int*   rpi    = (const int*)d_in[12];

  char* w = (char*)d_ws;
  float*  bias_table = (float*)(w + 0);               //   7200 B
  float*  relb       = (float*)(w + 8192);            // 131072 B
  ushort* qkvWT      = (ushort*)(w + 139264);         // 393216 B  [768][256] bf16
  ushort* projWT     = (ushort*)(w + 532480);         // 131072 B  [256][256] bf16
  ushort* xb         = (ushort*)(w + 663552);         // 67108864 B [131072][256] bf16
  ushort* qkvb       = (ushort*)(w + 67772416ull);    // 201326592 B [131072][768] bf16
  ushort* aob        = (ushort*)(w + 269099008ull);   // 67108864 B [131072][256] bf16
  (void)ws_size; (void)n_in; (void)in_sizes; (void)out_size;

  k_cast_bf16<<<4096, 256, 0, stream>>>(x, xb, MROWS * CDIM / 4);
  k_transpose_bf16<<<768, 256, 0, stream>>>(qkv_w, qkvWT, 256, 768);
  k_transpose_bf16<<<256, 256, 0, stream>>>(projw, projWT, 256, 256);
  k_cpb<<<225, 256, 0, stream>>>(ctbl, m1w, m1b, m2w, bias_table);
  k_relb<<<128, 256, 0, stream>>>(bias_table, rpi, relb);

  gemm_bt<0><<<dim3(6, 1024), 256, 0, stream>>>(xb, qkvWT, qkvb, q_bias, v_bias, 256, 768);
  k_attn<<<BWIN, 256, 0, stream>>>(qkvb, mask, lscale, relb, aob);
  gemm_bt<1><<<dim3(2, 1024), 256, 0, stream>>>(aob, projWT, d_out, projb, nullptr, 256, 256);
}

// Round 2
// 504.793 us; speedup vs baseline: 1.4669x; 1.4669x over previous
//
#include <hip/hip_runtime.h>
#include <hip/hip_bf16.h>
#include <stdint.h>

// Problem constants
#define NTOK   64      // tokens per window
#define CDIM   256     // embed dim
#define NHEAD  8
#define DHEAD  32
#define NWIN   256     // windows per image (mask count)
#define BWIN   2048    // total windows
#define MROWS  131072  // BWIN*NTOK

typedef __attribute__((ext_vector_type(8))) short short8;
typedef __attribute__((ext_vector_type(4))) float f32x4;

__device__ __forceinline__ ushort f2bf(float f) {
  uint32_t u = __float_as_uint(f);
  u += 0x7fffu + ((u >> 16) & 1u);   // RNE
  return (ushort)(u >> 16);
}
__device__ __forceinline__ void unpack8(uint4 u, float* f) {
  f[0] = __uint_as_float(u.x << 16);
  f[1] = __uint_as_float(u.x & 0xffff0000u);
  f[2] = __uint_as_float(u.y << 16);
  f[3] = __uint_as_float(u.y & 0xffff0000u);
  f[4] = __uint_as_float(u.z << 16);
  f[5] = __uint_as_float(u.z & 0xffff0000u);
  f[6] = __uint_as_float(u.w << 16);
  f[7] = __uint_as_float(u.w & 0xffff0000u);
}

// ---------------- tiny prep kernels ----------------

__global__ void k_cast_bf16(const float* __restrict__ src, ushort* __restrict__ dst, int n4) {
  int i = blockIdx.x * blockDim.x + threadIdx.x;
  int stride = gridDim.x * blockDim.x;
  for (; i < n4; i += stride) {
    float4 v = ((const float4*)src)[i];
    ushort4 o;
    o.x = f2bf(v.x); o.y = f2bf(v.y); o.z = f2bf(v.z); o.w = f2bf(v.w);
    ((ushort4*)dst)[i] = o;
  }
}

// src[K][N] fp32 -> dst[N][K] bf16
__global__ void k_transpose_bf16(const float* __restrict__ src, ushort* __restrict__ dst, int K, int N) {
  int idx = blockIdx.x * 256 + threadIdx.x;
  if (idx < N * K) {
    int n = idx / K, k = idx - n * K;
    dst[idx] = f2bf(src[(size_t)k * N + n]);
  }
}

// CPB MLP: bias_table[225][8]
__global__ void k_cpb(const float* __restrict__ ct, const float* __restrict__ w1,
                      const float* __restrict__ b1, const float* __restrict__ w2,
                      float* __restrict__ out) {
  int p = blockIdx.x, t = threadIdx.x;
  float c0 = ct[p * 2], c1 = ct[p * 2 + 1];
  float acc[8];
#pragma unroll
  for (int h = 0; h < 8; ++h) acc[h] = 0.f;
  for (int j = t; j < 512; j += 256) {
    float hj = fmaxf(0.f, fmaf(c0, w1[j], fmaf(c1, w1[512 + j], b1[j])));
#pragma unroll
    for (int h = 0; h < 8; ++h) acc[h] = fmaf(hj, w2[j * 8 + h], acc[h]);
  }
#pragma unroll
  for (int off = 1; off < 64; off <<= 1)
#pragma unroll
    for (int h = 0; h < 8; ++h) acc[h] += __shfl_xor(acc[h], off, 64);
  __shared__ float red[4][8];
  if ((t & 63) == 0)
#pragma unroll
    for (int h = 0; h < 8; ++h) red[t >> 6][h] = acc[h];
  __syncthreads();
  if (t < 8) out[p * 8 + t] = red[0][t] + red[1][t] + red[2][t] + red[3][t];
}

// relbC in MFMA C-fragment order: idx = ((((h*4+mt)*4+nt)*4+g)*16+l16)*4+reg
// value = 16*sigmoid(bias_table[rpi[r*64+c]][h]), r = mt*16+g*4+reg, c = nt*16+l16
__global__ void k_relbC(const float* __restrict__ bt, const int* __restrict__ rpi,
                        float* __restrict__ out) {
  int idx = blockIdx.x * 256 + threadIdx.x;  // 32768 total
  int reg = idx & 3, l16 = (idx >> 2) & 15, g = (idx >> 6) & 3;
  int nt = (idx >> 8) & 3, mt = (idx >> 10) & 3, h = idx >> 12;
  int r = mt * 16 + g * 4 + reg, c = nt * 16 + l16;
  float v = bt[rpi[r * 64 + c] * 8 + h];
  out[idx] = 16.0f / (1.0f + __expf(-v));
}

// maskC in MFMA C-fragment order: idx = ((((wi*4+mt)*4+nt)*4+g)*16+l16)*4+reg
__global__ void k_maskC(const float* __restrict__ mask, float* __restrict__ out) {
  int idx = blockIdx.x * 256 + threadIdx.x;  // 1048576 total
  int reg = idx & 3, l16 = (idx >> 2) & 15, g = (idx >> 6) & 3;
  int nt = (idx >> 8) & 3, mt = (idx >> 10) & 3, wi = idx >> 12;
  int r = mt * 16 + g * 4 + reg, c = nt * 16 + l16;
  out[idx] = mask[(size_t)wi * 4096 + r * 64 + c];
}

// ---------------- MFMA GEMM: C[M][N] = A[M][K] * BT[N][K]^T ----------------
template <int MODE>
__global__ __launch_bounds__(256, 2) void gemm_bt(const ushort* __restrict__ A,
                                                  const ushort* __restrict__ BT,
                                                  void* __restrict__ Cout,
                                                  const float* __restrict__ bias0,
                                                  const float* __restrict__ bias1,
                                                  int K, int N) {
  __shared__ ushort As[128 * 64];
  __shared__ ushort Bs[128 * 64];
  const int t = threadIdx.x;
  const int bn = blockIdx.x, bm = blockIdx.y;
  const int wv = t >> 6, lane = t & 63, quad = lane >> 4, l16 = lane & 15;
  const int mbase = (wv & 1) * 64, nbase = (wv >> 1) * 64;

  f32x4 acc[4][4] = {};

  const int nkt = K >> 6;
  for (int kt = 0; kt < nkt; ++kt) {
    __syncthreads();
#pragma unroll
    for (int i = 0; i < 4; ++i) {
      int idx = i * 256 + t;
      int m = idx >> 3, c = idx & 7;
      int sw = (m * 8 + (c ^ (m & 7))) * 8;
      *(uint4*)(As + sw) = *(const uint4*)(A + (size_t)(bm * 128 + m) * K + kt * 64 + c * 8);
      *(uint4*)(Bs + sw) = *(const uint4*)(BT + (size_t)(bn * 128 + m) * K + kt * 64 + c * 8);
    }
    __syncthreads();
#pragma unroll
    for (int k2 = 0; k2 < 2; ++k2) {
      const int cidx = (k2 * 4 + quad) ^ (l16 & 7);
      short8 a[4], b[4];
#pragma unroll
      for (int mt = 0; mt < 4; ++mt)
        a[mt] = *(const short8*)(As + ((mbase + mt * 16 + l16) * 8 + cidx) * 8);
#pragma unroll
      for (int nt = 0; nt < 4; ++nt)
        b[nt] = *(const short8*)(Bs + ((nbase + nt * 16 + l16) * 8 + cidx) * 8);
#pragma unroll
      for (int mt = 0; mt < 4; ++mt)
#pragma unroll
        for (int nt = 0; nt < 4; ++nt)
          acc[mt][nt] = __builtin_amdgcn_mfma_f32_16x16x32_bf16(a[mt], b[nt], acc[mt][nt], 0, 0, 0);
    }
  }

#pragma unroll
  for (int mt = 0; mt < 4; ++mt)
#pragma unroll
    for (int nt = 0; nt < 4; ++nt) {
      int j = bn * 128 + nbase + nt * 16 + l16;
      int gm = bm * 128 + mbase + mt * 16 + quad * 4;
      float bs;
      if (MODE == 0) bs = (j < 256) ? bias0[j] : ((j < 512) ? 0.0f : bias1[j - 512]);
      else bs = bias0[j];
#pragma unroll
      for (int i2 = 0; i2 < 4; ++i2) {
        float v = acc[mt][nt][i2] + bs;
        size_t off = (size_t)(gm + i2) * N + j;
        if (MODE == 0) ((ushort*)Cout)[off] = f2bf(v);
        else ((float*)Cout)[off] = v;
      }
    }
}

// ---------------- MFMA attention ----------------
// 1 block / window, 4 waves. 2 passes of 4 heads; wave wv owns head pass*4+wv.
// LDS: Qs (scale*q/||q||), Ks (k/||k||) bf16 [4][64][40]; Vt bf16 [4][32][72];
// Ps: per-wave P chunk [64][40] for the C->A layout round-trip.
// S = QK^T via 16 mfma (K=32, one step); softmax rows via shfl over 16 lanes;
// PV via 2 K-steps x (4x2) mfma. relb/mask pre-permuted to C-frag order.
__global__ __launch_bounds__(256, 2) void k_attn_mfma(const ushort* __restrict__ qkv,
                                                      const float* __restrict__ maskC,
                                                      const float* __restrict__ ls,
                                                      const float* __restrict__ relbC,
                                                      ushort* __restrict__ aob) {
  __shared__ ushort Qs[4][64][40];
  __shared__ ushort Ks[4][64][40];
  __shared__ ushort Vt[4][32][72];
  __shared__ ushort Ps[4][64][40];
  const int b = blockIdx.x, t = threadIdx.x;
  const int wi = b & (NWIN - 1);
  const int wv = t >> 6, lane = t & 63;
  const int g = lane >> 4, l16 = lane & 15;

  for (int pass = 0; pass < 2; ++pass) {
    __syncthreads();  // protect LDS reuse across passes
    // ---- staging: thread = (head-sub hh=wv, token=lane) ----
    {
      const int hh = wv, tok = lane;
      const int h = pass * 4 + hh;
      const size_t base = ((size_t)b * 64 + tok) * 768 + h * 32;
      // Q: normalize + fold logit scale
      {
        union { uint4 u[4]; ushort s[32]; } raw, outp;
        raw.u[0] = *(const uint4*)(qkv + base);
        raw.u[1] = *(const uint4*)(qkv + base + 8);
        raw.u[2] = *(const uint4*)(qkv + base + 16);
        raw.u[3] = *(const uint4*)(qkv + base + 24);
        float f[32];
#pragma unroll
        for (int c = 0; c < 4; ++c) unpack8(raw.u[c], f + c * 8);
        float s = 0.f;
#pragma unroll
        for (int j = 0; j < 32; ++j) s = fmaf(f[j], f[j], s);
        float sc = __expf(fminf(ls[h], 4.6051701859880914f));
        float fac = sc / fmaxf(sqrtf(s), 1e-12f);
#pragma unroll
        for (int j = 0; j < 32; ++j) outp.s[j] = f2bf(f[j] * fac);
#pragma unroll
        for (int c = 0; c < 4; ++c) *(uint4*)&Qs[hh][tok][c * 8] = outp.u[c];
      }
      // K: normalize
      {
        union { uint4 u[4]; ushort s[32]; } raw, outp;
        raw.u[0] = *(const uint4*)(qkv + base + 256);
        raw.u[1] = *(const uint4*)(qkv + base + 264);
        raw.u[2] = *(const uint4*)(qkv + base + 272);
        raw.u[3] = *(const uint4*)(qkv + base + 280);
        float f[32];
#pragma unroll
        for (int c = 0; c < 4; ++c) unpack8(raw.u[c], f + c * 8);
        float s = 0.f;
#pragma unroll
        for (int j = 0; j < 32; ++j) s = fmaf(f[j], f[j], s);
        float fac = 1.0f / fmaxf(sqrtf(s), 1e-12f);
#pragma unroll
        for (int j = 0; j < 32; ++j) outp.s[j] = f2bf(f[j] * fac);
#pragma unroll
        for (int c = 0; c < 4; ++c) *(uint4*)&Ks[hh][tok][c * 8] = outp.u[c];
      }
      // V: raw bf16 scatter into transposed layout Vt[dim][tok]
      {
        union { uint4 u[4]; ushort s[32]; } raw;
        raw.u[0] = *(const uint4*)(qkv + base + 512);
        raw.u[1] = *(const uint4*)(qkv + base + 520);
        raw.u[2] = *(const uint4*)(qkv + base + 528);
        raw.u[3] = *(const uint4*)(qkv + base + 536);
#pragma unroll
        for (int d = 0; d < 32; ++d) Vt[hh][d][tok] = raw.s[d];
      }
    }
    __syncthreads();

    const int h = pass * 4 + wv;
    // ---- S = Qn * Kn^T  (16 mfma, K=32 in one step) ----
    short8 qfr[4], kfr[4];
#pragma unroll
    for (int mt = 0; mt < 4; ++mt) qfr[mt] = *(const short8*)&Qs[wv][mt * 16 + l16][g * 8];
#pragma unroll
    for (int nt = 0; nt < 4; ++nt) kfr[nt] = *(const short8*)&Ks[wv][nt * 16 + l16][g * 8];
    f32x4 sv[4][4];
    const f32x4 zero = {0.f, 0.f, 0.f, 0.f};
#pragma unroll
    for (int mt = 0; mt < 4; ++mt)
#pragma unroll
      for (int nt = 0; nt < 4; ++nt)
        sv[mt][nt] = __builtin_amdgcn_mfma_f32_16x16x32_bf16(qfr[mt], kfr[nt], zero, 0, 0, 0);

    // ---- + relb + mask (C-frag-ordered float4 loads) ----
#pragma unroll
    for (int mt = 0; mt < 4; ++mt)
#pragma unroll
      for (int nt = 0; nt < 4; ++nt) {
        float4 rb = *(const float4*)(relbC + (size_t)(((h * 4 + mt) * 4 + nt) * 4 + g) * 64 + l16 * 4);
        float4 mk = *(const float4*)(maskC + (size_t)(((wi * 4 + mt) * 4 + nt) * 4 + g) * 64 + l16 * 4);
        sv[mt][nt][0] += rb.x + mk.x;
        sv[mt][nt][1] += rb.y + mk.y;
        sv[mt][nt][2] += rb.z + mk.z;
        sv[mt][nt][3] += rb.w + mk.w;
      }

    // ---- softmax over rows (row r = mt*16 + g*4 + reg; 64 cols over nt,l16) ----
    float mx[4][4], inv[4][4];
#pragma unroll
    for (int mt = 0; mt < 4; ++mt)
#pragma unroll
      for (int reg = 0; reg < 4; ++reg) {
        float m = fmaxf(fmaxf(sv[mt][0][reg], sv[mt][1][reg]),
                        fmaxf(sv[mt][2][reg], sv[mt][3][reg]));
#pragma unroll
        for (int st = 1; st < 16; st <<= 1) m = fmaxf(m, __shfl_xor(m, st, 64));
        mx[mt][reg] = m;
      }
#pragma unroll
    for (int mt = 0; mt < 4; ++mt)
#pragma unroll
      for (int nt = 0; nt < 4; ++nt)
#pragma unroll
        for (int reg = 0; reg < 4; ++reg)
          sv[mt][nt][reg] = __expf(sv[mt][nt][reg] - mx[mt][reg]);
#pragma unroll
    for (int mt = 0; mt < 4; ++mt)
#pragma unroll
      for (int reg = 0; reg < 4; ++reg) {
        float s = sv[mt][0][reg] + sv[mt][1][reg] + sv[mt][2][reg] + sv[mt][3][reg];
#pragma unroll
        for (int st = 1; st < 16; st <<= 1) s += __shfl_xor(s, st, 64);
        inv[mt][reg] = 1.0f / s;
      }

    // ---- PV: P (C-layout) -> LDS -> A-frags; O += P * V ----
    f32x4 ov[4][2] = {};
#pragma unroll
    for (int kt = 0; kt < 2; ++kt) {
      __syncthreads();
#pragma unroll
      for (int mt = 0; mt < 4; ++mt)
#pragma unroll
        for (int reg = 0; reg < 4; ++reg)
#pragma unroll
          for (int tjh = 0; tjh < 2; ++tjh)
            Ps[wv][mt * 16 + g * 4 + reg][tjh * 16 + l16] = f2bf(sv[mt][kt * 2 + tjh][reg]);
      __syncthreads();
      short8 pf[4], vf[2];
#pragma unroll
      for (int mt = 0; mt < 4; ++mt) pf[mt] = *(const short8*)&Ps[wv][mt * 16 + l16][g * 8];
#pragma unroll
      for (int n2 = 0; n2 < 2; ++n2) vf[n2] = *(const short8*)&Vt[wv][n2 * 16 + l16][kt * 32 + g * 8];
#pragma unroll
      for (int mt = 0; mt < 4; ++mt)
#pragma unroll
        for (int n2 = 0; n2 < 2; ++n2)
          ov[mt][n2] = __builtin_amdgcn_mfma_f32_16x16x32_bf16(pf[mt], vf[n2], ov[mt][n2], 0, 0, 0);
    }

    // ---- epilogue: normalize rows, store bf16 ----
#pragma unroll
    for (int mt = 0; mt < 4; ++mt)
#pragma unroll
      for (int n2 = 0; n2 < 2; ++n2)
#pragma unroll
        for (int reg = 0; reg < 4; ++reg) {
          int r = mt * 16 + g * 4 + reg;
          float o = ov[mt][n2][reg] * inv[mt][reg];
          aob[((size_t)b * 64 + r) * 256 + h * 32 + n2 * 16 + l16] = f2bf(o);
        }
  }
}

// ---------------- launch ----------------

extern "C" void kernel_launch(void* const* d_in, const int* in_sizes, int n_in,
                              void* d_out, int out_size, void* d_ws, size_t ws_size,
                              hipStream_t stream) {
  const float* x      = (const float*)d_in[0];
  const float* mask   = (const float*)d_in[1];
  const float* qkv_w  = (const float*)d_in[2];
  const float* q_bias = (const float*)d_in[3];
  const float* v_bias = (const float*)d_in[4];
  const float* lscale = (const float*)d_in[5];
  const float* ctbl   = (const float*)d_in[6];
  const float* m1w    = (const float*)d_in[7];
  const float* m1b    = (const float*)d_in[8];
  const float* m2w    = (const float*)d_in[9];
  const float* projw  = (const float*)d_in[10];
  const float* projb  = (const float*)d_in[11];
  const int*   rpi    = (const int*)d_in[12];

  char* w = (char*)d_ws;
  float*  bias_table = (float*)(w + 0);               //    7200 B
  float*  relbC      = (float*)(w + 8192);            //  131072 B
  float*  maskC      = (float*)(w + 139264);          // 4194304 B
  ushort* qkvWT      = (ushort*)(w + 4333568);        //  393216 B  [768][256] bf16
  ushort* projWT     = (ushort*)(w + 4726784);        //  131072 B  [256][256] bf16
  ushort* xb         = (ushort*)(w + 4857856);        // 67108864 B [131072][256] bf16
  ushort* qkvb       = (ushort*)(w + 71966720ull);    // 201326592 B [131072][768] bf16
  ushort* aob        = (ushort*)(w + 273293312ull);   // 67108864 B [131072][256] bf16
  (void)ws_size; (void)n_in; (void)in_sizes; (void)out_size;

  k_cast_bf16<<<4096, 256, 0, stream>>>(x, xb, MROWS * CDIM / 4);
  k_transpose_bf16<<<768, 256, 0, stream>>>(qkv_w, qkvWT, 256, 768);
  k_transpose_bf16<<<256, 256, 0, stream>>>(projw, projWT, 256, 256);
  k_cpb<<<225, 256, 0, stream>>>(ctbl, m1w, m1b, m2w, bias_table);
  k_relbC<<<128, 256, 0, stream>>>(bias_table, rpi, relbC);
  k_maskC<<<4096, 256, 0, stream>>>(mask, maskC);

  gemm_bt<0><<<dim3(6, 1024), 256, 0, stream>>>(xb, qkvWT, qkvb, q_bias, v_bias, 256, 768);
  k_attn_mfma<<<BWIN, 256, 0, stream>>>(qkvb, maskC, lscale, relbC, aob);
  gemm_bt<1><<<dim3(2, 1024), 256, 0, stream>>>(aob, projWT, d_out, projb, nullptr, 256, 256);
}